// Round 9
// baseline (289.404 us; speedup 1.0000x reference)
//
#include <hip/hip_runtime.h>

// EOQLinear: int4-quantized GEMV.
//   out[n] = sum_b scales[n,b] * sum_{q in block b} w_int[n,q] * x[q]
// packed_w[n,j] is an int32 in [0,256): low nibble -> k=2j, high nibble -> k=2j+1,
// both offset by -8.
//
// DTYPE NOTE (round-1): harness stages the reference's float16 tensors as FLOAT32.
//
// ROUND-9 post-mortem of the round-8 probe:
//   harness overhead ~143 us (two independent estimates agree); single-pass
//   kernel time ~54 us. Cold weight stream ran at 2.4 TB/s HBM while warm
//   (L3-hit) passes hit 6.3 TB/s LOGICAL with the same ~2.2 TB/s HBM residual
//   -> LATENCY-BOUND (in-flight bytes), not DRAM-pattern-bound. VGPR=44 shows
//   the compiler never software-pipelined; VALUBusy 22% = compute/latency duty
//   cycle; ~8-16 KiB in flight per CU vs ~22 KiB Little's-law need @900 cyc.
//
// ROUND-9 CHANGE: explicit prefetch ring, depth PF=4. One row per wave
// (2048 blocks -> 8 blocks/CU of work). Prologue issues 4 chunks' loads
// (weights int4 + two float4 of x); each iter consumes slot t&3, computes,
// and issues chunk t+PF into the slot. Guaranteed ~4 KiB weight bytes in
// flight per wave; __launch_bounds__(256,4) -> <=128 VGPR -> 16 waves/CU
// -> ~64 KiB/CU in flight (~3x requirement). Scales: blocksPerRow(=64) <= 64
// so one scale per lane preloaded once; per-iter value via __shfl (no scale
// loads in the vmcnt queue).

#define PF 4  // prefetch depth (power of 2)

template<bool SHFL_SCALES>
__global__ __launch_bounds__(256, 4)
void eoq_gemv_kernel(const float* __restrict__ x,
                     const int* __restrict__ packed_w,
                     const float* __restrict__ scales,
                     float* __restrict__ out,
                     int N, int halfK, int iters, int sShift, int blocksPerRow)
{
    const int lane = threadIdx.x & 63;
    const int wave = threadIdx.x >> 6;
    const int row  = blockIdx.x * 4 + wave;
    if (row >= N) return;

    const int4*   __restrict__ w4p =
        reinterpret_cast<const int4*>(packed_w + (size_t)row * halfK);
    const float4* __restrict__ x4p = reinterpret_cast<const float4*>(x);
    const float*  __restrict__ srow = scales + (size_t)row * blocksPerRow;

    // Preload this row's scales across lanes (one scale per lane).
    float sAll = 0.f;
    if (SHFL_SCALES) {
        sAll = (lane < blocksPerRow) ? srow[lane] : 0.f;
    }

    int4   wbuf[PF];
    float4 xabuf[PF];
    float4 xbbuf[PF];

    // Prologue: fill the ring with chunks 0..PF-1 (clamped if iters < PF).
    #pragma unroll
    for (int p = 0; p < PF; ++p) {
        const int c  = (p < iters) ? p : (iters - 1);
        const int j4 = (c << 6) + lane;          // 16B-chunk index in the row
        wbuf[p]  = w4p[j4];
        xabuf[p] = x4p[2 * j4];
        xbbuf[p] = x4p[2 * j4 + 1];
    }

    float acc = 0.f;

    #pragma unroll 4
    for (int t = 0; t < iters; ++t) {
        const int slot = t & (PF - 1);
        const int4   w4 = wbuf[slot];
        const float4 xa = xabuf[slot];
        const float4 xb = xbbuf[slot];

        float s;
        if (SHFL_SCALES) {
            // scale index for (t, lane): ((t<<6)+lane) >> sShift, held by that lane
            s = __shfl(sAll, ((t << 6) + lane) >> sShift, 64);
        } else {
            s = srow[((t << 6) + lane) >> sShift];
        }

        const unsigned w0 = (unsigned)w4.x;
        const unsigned w1 = (unsigned)w4.y;
        const unsigned w2 = (unsigned)w4.z;
        const unsigned w3 = (unsigned)w4.w;

        float part = 0.f;
        part = fmaf((float)(int)(w0 & 0xFu) - 8.f, xa.x, part);
        part = fmaf((float)(int)(w0 >> 4)   - 8.f, xa.y, part);
        part = fmaf((float)(int)(w1 & 0xFu) - 8.f, xa.z, part);
        part = fmaf((float)(int)(w1 >> 4)   - 8.f, xa.w, part);
        part = fmaf((float)(int)(w2 & 0xFu) - 8.f, xb.x, part);
        part = fmaf((float)(int)(w2 >> 4)   - 8.f, xb.y, part);
        part = fmaf((float)(int)(w3 & 0xFu) - 8.f, xb.z, part);
        part = fmaf((float)(int)(w3 >> 4)   - 8.f, xb.w, part);
        acc = fmaf(s, part, acc);

        // Refill this slot with chunk t+PF (clamped at the tail; the few
        // redundant tail loads hit L1/L2).
        const int nc = (t + PF < iters) ? (t + PF) : (iters - 1);
        const int j4 = (nc << 6) + lane;
        wbuf[slot]  = w4p[j4];
        xabuf[slot] = x4p[2 * j4];
        xbbuf[slot] = x4p[2 * j4 + 1];
    }

    // wave-64 butterfly reduction
    #pragma unroll
    for (int off = 32; off > 0; off >>= 1)
        acc += __shfl_down(acc, off, 64);

    if (lane == 0) out[row] = acc;
}

extern "C" void kernel_launch(void* const* d_in, const int* in_sizes, int n_in,
                              void* d_out, int out_size, void* d_ws, size_t ws_size,
                              hipStream_t stream) {
    const float* x      = (const float*)d_in[0];
    const int*   pw     = (const int*)d_in[1];
    const float* scales = (const float*)d_in[2];
    float*       out    = (float*)d_out;

    const int K     = in_sizes[0];         // 8192
    const int halfK = K >> 1;              // 4096
    const int N     = in_sizes[1] / halfK; // 8192
    const int blocksPerRow = in_sizes[2] / N;    // K/QB = 64

    const int qhalf = halfK / blocksPerRow;      // QB/2 (pow2)
    int qhalfShift = 0;
    while ((1 << qhalfShift) < qhalf) ++qhalfShift;
    const int sShift = qhalfShift - 2;           // 16B-chunk idx -> qblock idx

    const int iters = halfK >> 8;                // 16 chunk-steps per row

    dim3 grid((N + 3) / 4), block(256);          // 1 row/wave, 4 waves/block
    if (blocksPerRow <= 64) {
        eoq_gemv_kernel<true><<<grid, block, 0, stream>>>(
            x, pw, scales, out, N, halfK, iters, sShift, blocksPerRow);
    } else {
        eoq_gemv_kernel<false><<<grid, block, 0, stream>>>(
            x, pw, scales, out, N, halfK, iters, sShift, blocksPerRow);
    }
}

// Round 10
// 198.300 us; speedup vs baseline: 1.4594x; 1.4594x over previous
//
#include <hip/hip_runtime.h>

// EOQLinear: int4-quantized GEMV.
//   out[n] = sum_b scales[n,b] * sum_{q in block b} w_int[n,q] * x[q]
// packed_w[n,j] is an int32 in [0,256): low nibble -> k=2j, high nibble -> k=2j+1,
// both offset by -8.
//
// DTYPE NOTE (round-1): harness stages the reference's float16 tensors as FLOAT32.
//
// ROUND-10 post-mortem of round 9: the dynamic-index prefetch ring was promoted
// out of registers (LDS_Block_Size=16384 with zero declared __shared__ = the
// 16 KB wbuf alloca in LDS; WRITE_SIZE ~300 MB = scratch spill for the float4
// rings; 5.5M LDS bank conflicts; VALUBusy 6%). Kernel 54 -> ~146 us. The
// round-8 latency-bound diagnosis stands (cold 2.4 TB/s vs warm-L3 6.3 TB/s
// logical at identical structure); the implementation was broken.
//
// ROUND-10: pipeline with COMPILE-TIME indices. Kernel templated on ITERS(=16)
// -> K-loop fully unrolls -> ring index (t & 7) becomes a literal -> ring stays
// in VGPRs. Depth-8 ring, loads issued in consumption order (w,xa,xb) 8 chunks
// ahead of use (~24 outstanding vmem/wave, ~8 KiB weight bytes in flight/wave).
// Scales via one-per-lane preload + __shfl (no scale loads in the vmcnt queue).
// __launch_bounds__(256,4): <=128 VGPR -> 16 waves/CU -> ~128 KiB in flight/CU
// (~6x Little's-law need at ~900 cyc HBM latency). 1 row/wave, 2048 blocks.
// Generic fallback kernel for non-(ITERS=16, blocksPerRow<=64) shapes.

#define DEPTH 8  // pipeline depth, power of 2, <= ITERS

template<int ITERS>
__global__ __launch_bounds__(256, 4)
void eoq_gemv_pipe(const float* __restrict__ x,
                   const int* __restrict__ packed_w,
                   const float* __restrict__ scales,
                   float* __restrict__ out,
                   int N, int halfK, int sShift, int blocksPerRow)
{
    const int lane = threadIdx.x & 63;
    const int wave = threadIdx.x >> 6;
    const int row  = blockIdx.x * 4 + wave;
    if (row >= N) return;

    const int4*   __restrict__ w4p =
        reinterpret_cast<const int4*>(packed_w + (size_t)row * halfK);
    const float4* __restrict__ x4p = reinterpret_cast<const float4*>(x);
    const float*  __restrict__ srow = scales + (size_t)row * blocksPerRow;

    // one scale per lane (blocksPerRow <= 64 on this path)
    const float sAll = (lane < blocksPerRow) ? srow[lane] : 0.f;

    int4   wr[DEPTH];
    float4 xar[DEPTH];
    float4 xbr[DEPTH];

    // Prologue: issue chunks 0..DEPTH-1 (consumption order: w, xa, xb).
    #pragma unroll
    for (int p = 0; p < DEPTH; ++p) {
        const int j4 = (p << 6) + lane;
        wr[p]  = w4p[j4];
        xar[p] = x4p[2 * j4];
        xbr[p] = x4p[2 * j4 + 1];
    }

    float acc = 0.f;

    #pragma unroll
    for (int t = 0; t < ITERS; ++t) {
        const int slot = t & (DEPTH - 1);   // literal after full unroll

        // Consume chunk t (forces wait only up to this chunk's loads).
        const int4   w4 = wr[slot];
        const float4 xa = xar[slot];
        const float4 xb = xbr[slot];

        // Refill the slot with chunk t+DEPTH before computing.
        if (t + DEPTH < ITERS) {
            const int j4 = ((t + DEPTH) << 6) + lane;
            wr[slot]  = w4p[j4];
            xar[slot] = x4p[2 * j4];
            xbr[slot] = x4p[2 * j4 + 1];
        }

        const float s = __shfl(sAll, ((t << 6) + lane) >> sShift, 64);

        const unsigned w0 = (unsigned)w4.x;
        const unsigned w1 = (unsigned)w4.y;
        const unsigned w2 = (unsigned)w4.z;
        const unsigned w3 = (unsigned)w4.w;

        float part = 0.f;
        part = fmaf((float)(int)(w0 & 0xFu) - 8.f, xa.x, part);
        part = fmaf((float)(int)(w0 >> 4)   - 8.f, xa.y, part);
        part = fmaf((float)(int)(w1 & 0xFu) - 8.f, xa.z, part);
        part = fmaf((float)(int)(w1 >> 4)   - 8.f, xa.w, part);
        part = fmaf((float)(int)(w2 & 0xFu) - 8.f, xb.x, part);
        part = fmaf((float)(int)(w2 >> 4)   - 8.f, xb.y, part);
        part = fmaf((float)(int)(w3 & 0xFu) - 8.f, xb.z, part);
        part = fmaf((float)(int)(w3 >> 4)   - 8.f, xb.w, part);
        acc = fmaf(s, part, acc);
    }

    #pragma unroll
    for (int off = 32; off > 0; off >>= 1)
        acc += __shfl_down(acc, off, 64);

    if (lane == 0) out[row] = acc;
}

// Generic fallback: plain loop, direct scale loads (any iters / blocksPerRow).
__global__ __launch_bounds__(256, 2)
void eoq_gemv_generic(const float* __restrict__ x,
                      const int* __restrict__ packed_w,
                      const float* __restrict__ scales,
                      float* __restrict__ out,
                      int N, int halfK, int iters, int sShift, int blocksPerRow)
{
    const int lane = threadIdx.x & 63;
    const int wave = threadIdx.x >> 6;
    const int row  = blockIdx.x * 4 + wave;
    if (row >= N) return;

    const int4*   __restrict__ w4p =
        reinterpret_cast<const int4*>(packed_w + (size_t)row * halfK);
    const float4* __restrict__ x4p = reinterpret_cast<const float4*>(x);
    const float*  __restrict__ srow = scales + (size_t)row * blocksPerRow;

    float acc = 0.f;
    #pragma unroll 2
    for (int it = 0; it < iters; ++it) {
        const int j4 = (it << 6) + lane;
        const int4   w4 = w4p[j4];
        const float4 xa = x4p[2 * j4];
        const float4 xb = x4p[2 * j4 + 1];
        const float  s  = srow[j4 >> sShift];

        const unsigned w0 = (unsigned)w4.x;
        const unsigned w1 = (unsigned)w4.y;
        const unsigned w2 = (unsigned)w4.z;
        const unsigned w3 = (unsigned)w4.w;

        float part = 0.f;
        part = fmaf((float)(int)(w0 & 0xFu) - 8.f, xa.x, part);
        part = fmaf((float)(int)(w0 >> 4)   - 8.f, xa.y, part);
        part = fmaf((float)(int)(w1 & 0xFu) - 8.f, xa.z, part);
        part = fmaf((float)(int)(w1 >> 4)   - 8.f, xa.w, part);
        part = fmaf((float)(int)(w2 & 0xFu) - 8.f, xb.x, part);
        part = fmaf((float)(int)(w2 >> 4)   - 8.f, xb.y, part);
        part = fmaf((float)(int)(w3 & 0xFu) - 8.f, xb.z, part);
        part = fmaf((float)(int)(w3 >> 4)   - 8.f, xb.w, part);
        acc = fmaf(s, part, acc);
    }

    #pragma unroll
    for (int off = 32; off > 0; off >>= 1)
        acc += __shfl_down(acc, off, 64);

    if (lane == 0) out[row] = acc;
}

extern "C" void kernel_launch(void* const* d_in, const int* in_sizes, int n_in,
                              void* d_out, int out_size, void* d_ws, size_t ws_size,
                              hipStream_t stream) {
    const float* x      = (const float*)d_in[0];
    const int*   pw     = (const int*)d_in[1];
    const float* scales = (const float*)d_in[2];
    float*       out    = (float*)d_out;

    const int K     = in_sizes[0];         // 8192
    const int halfK = K >> 1;              // 4096
    const int N     = in_sizes[1] / halfK; // 8192
    const int blocksPerRow = in_sizes[2] / N;    // K/QB = 64

    const int qhalf = halfK / blocksPerRow;      // QB/2 (pow2)
    int qhalfShift = 0;
    while ((1 << qhalfShift) < qhalf) ++qhalfShift;
    const int sShift = qhalfShift - 2;           // 16B-chunk idx -> qblock idx

    const int iters = halfK >> 8;                // 16 chunk-steps per row

    dim3 grid((N + 3) / 4), block(256);          // 1 row/wave, 4 waves/block
    if (iters == 16 && blocksPerRow <= 64) {
        eoq_gemv_pipe<16><<<grid, block, 0, stream>>>(
            x, pw, scales, out, N, halfK, sShift, blocksPerRow);
    } else {
        eoq_gemv_generic<<<grid, block, 0, stream>>>(
            x, pw, scales, out, N, halfK, iters, sShift, blocksPerRow);
    }
}